// Round 3
// baseline (440.763 us; speedup 1.0000x reference)
//
#include <hip/hip_runtime.h>

typedef float f4 __attribute__((ext_vector_type(4)));
typedef short s8 __attribute__((ext_vector_type(8)));
typedef unsigned short u16x4 __attribute__((ext_vector_type(4)));

// ---- ws layout (bytes) ----
// embB   : 1 MiB    .. 5 MiB   (4096*512 bf16)
// rbT    : 5 MiB    .. 37 MiB  (64*512*512 bf16, [n][o][i])
// gemmT  : 37 MiB   .. 53 MiB  (2 slices of 512*4096 f32, [o][b])

__device__ __forceinline__ unsigned short f2bf(float f) {
    unsigned int u = __float_as_uint(f);
    unsigned int r = (u + 0x7fffu + ((u >> 16) & 1u)) >> 16;
    return (unsigned short)r;
}

__global__ void cvt_emb(const float* __restrict__ e, unsigned short* __restrict__ eb) {
    int g = (blockIdx.x * 256 + threadIdx.x) * 4;
    f4 v = *(const f4*)(e + g);
    u16x4 o;
    o[0] = f2bf(v[0]); o[1] = f2bf(v[1]); o[2] = f2bf(v[2]); o[3] = f2bf(v[3]);
    *(u16x4*)(eb + g) = o;
}

// rbT[n][o][i] = bf16(rel_base[n][i][o])
__global__ void transpose_rb(const float* __restrict__ rb, unsigned short* __restrict__ rbT) {
    __shared__ float tl[32][33];
    int n = blockIdx.z, i0 = blockIdx.x * 32, o0 = blockIdx.y * 32;
    int tx = threadIdx.x, ty = threadIdx.y;      // 32 x 8
#pragma unroll
    for (int k = 0; k < 4; k++) {
        int i = ty + k * 8;
        tl[i][tx] = rb[((size_t)(n * 512 + i0 + i)) * 512 + o0 + tx];
    }
    __syncthreads();
#pragma unroll
    for (int k = 0; k < 4; k++) {
        int o = ty + k * 8;
        rbT[((size_t)(n * 512 + o0 + o)) * 512 + i0 + tx] = f2bf(tl[tx][o]);
    }
}

// Main fused GEMM, barrier-free per-wave pipeline, n-split x2:
// gemmT[z][o][b] = sum_{n in half z} att[b,n] * sum_i emb[b,i]*rbT[n][o][i]
// block: 64 b (m) x 64 o; 4 waves, wave tile = 16 o x 64 m.
// K-chunk 64/iter, A-fragments loaded straight to VGPRs (dbuf), NO inner barrier.
// LDS = attS only (8 KiB). Grid swizzle: o-slice == XCD -> rbT slice (4 MiB) L2-resident.
__global__ __launch_bounds__(256, 4) void gemm_fold(const unsigned short* __restrict__ embB,
                                                    const unsigned short* __restrict__ rbT,
                                                    const int* __restrict__ ids,
                                                    const float* __restrict__ rel_att,
                                                    float* __restrict__ gemmT) {
    __shared__ float attS[64][32];                // [m][n ^ (m&31)] swizzle, no pad

    const int t = threadIdx.x;
    const int wv = t >> 6;
    const int ln = t & 63;
    const int q  = ln >> 4;     // quad 0..3
    const int lm = ln & 15;
    const int g  = blockIdx.x;
    const int o0 = (g & 7) * 64;                  // fastest -> XCD-aligned o slice
    const int m0 = ((g >> 3) & 63) * 64;
    const int nz = g >> 9;                        // n-half 0/1
    const int nbase = nz * 32;

    // stage att tile [64 m][32 n] (swizzled), gather via ids: 8 per thread
#pragma unroll
    for (int k = 0; k < 8; k++) {
        int idx = t + 256 * k;
        int m = idx >> 5, n = idx & 31;
        attS[m][n ^ (m & 31)] = rel_att[(size_t)ids[m0 + m] * 64 + nbase + n];
    }
    __syncthreads();                              // the ONLY barrier

    // this lane's A-fragment base: row o = o0 + wv*16 + lm, i offset q*8
    const unsigned short* aBase = rbT + ((size_t)(nbase * 512) + (o0 + wv * 16 + lm)) * 512 + q * 8;

    s8 embF[2][4];
    s8 A0[2], A1[2];
    f4 z = {0.f, 0.f, 0.f, 0.f};
    f4 acc[4] = {z, z, z, z};

    // s = ic*32 + nl, ic in [0,8), nl in [0,32)
#define LDB(S, A)                                                                  \
    {                                                                              \
        const unsigned short* p = aBase + (size_t)((S) & 31) * 262144 + ((S) >> 5) * 64; \
        A[0] = *(const s8*)(p);                                                    \
        A[1] = *(const s8*)(p + 32);                                               \
    }

#define COMPUTE(A, S)                                                              \
    {                                                                              \
        f4 an[4];                                                                  \
        _Pragma("unroll")                                                          \
        for (int ms = 0; ms < 4; ms++)                                             \
            an[ms] = __builtin_amdgcn_mfma_f32_16x16x32_bf16(A[0], embF[0][ms], z, 0, 0, 0); \
        _Pragma("unroll")                                                          \
        for (int ms = 0; ms < 4; ms++)                                             \
            an[ms] = __builtin_amdgcn_mfma_f32_16x16x32_bf16(A[1], embF[1][ms], an[ms], 0, 0, 0); \
        int nl = (S) & 31;                                                         \
        _Pragma("unroll")                                                          \
        for (int ms = 0; ms < 4; ms++) {                                           \
            int mr = ms * 16 + lm;                                                 \
            float av = attS[mr][nl ^ (mr & 31)];                                   \
            acc[ms] += av * an[ms];                                                \
        }                                                                          \
    }

    LDB(0, A0);
    for (int s = 0; s < 256; s += 2) {
        if ((s & 31) == 0) {
            int ic = s >> 5;
#pragma unroll
            for (int ks = 0; ks < 2; ks++)
#pragma unroll
                for (int ms = 0; ms < 4; ms++)
                    embF[ks][ms] = *(const s8*)(embB + (size_t)(m0 + ms * 16 + lm) * 512
                                                + ic * 64 + ks * 32 + q * 8);
        }
        LDB(s + 1, A1);
        COMPUTE(A0, s);
        if (s + 2 < 256) LDB(s + 2, A0);
        COMPUTE(A1, s + 1);
    }
#undef LDB
#undef COMPUTE

    // epilogue: D[row=o][col=m] into this half's slice
    float* gT = gemmT + (size_t)nz * 512 * 4096;
#pragma unroll
    for (int ms = 0; ms < 4; ms++)
#pragma unroll
        for (int r = 0; r < 4; r++) {
            int o = o0 + wv * 16 + q * 4 + r;
            int m = m0 + ms * 16 + lm;
            gT[(size_t)o * 4096 + m] = acc[ms][r];
        }
}

// LayerNorm over o (512) per b: v = g0+g1+bias, bias computed in-kernel from
// att (gathered via ids) x rel_bias (L2-resident, 128 KB). Writes out[b][o].
__global__ __launch_bounds__(256) void ln_kernel(const float* __restrict__ g0,
                                                 const float* __restrict__ g1,
                                                 const int* __restrict__ ids,
                                                 const float* __restrict__ rel_att,
                                                 const float* __restrict__ relb,
                                                 float* __restrict__ out) {
    __shared__ float S[512][17];
    __shared__ float attL[16][65];
    int t = threadIdx.x;
    int b0 = blockIdx.x * 16;

    {   // load att tile [16 b][64 n]: 4 per thread, gathered
        int idx = t * 4;
        int b = idx >> 6, n = idx & 63;
        f4 v = *(const f4*)(rel_att + (size_t)ids[b0 + b] * 64 + n);
        attL[b][n] = v[0]; attL[b][n + 1] = v[1]; attL[b][n + 2] = v[2]; attL[b][n + 3] = v[3];
    }
    // phase 1: S[o][b] = g0 + g1
#pragma unroll
    for (int p = 0; p < 8; p++) {
        int r = p * 64 + (t >> 2);
        int cb = (t & 3) * 4;
        f4 a = *(const f4*)(g0 + (size_t)r * 4096 + b0 + cb);
        f4 b = *(const f4*)(g1 + (size_t)r * 4096 + b0 + cb);
        f4 v = a + b;
        S[r][cb + 0] = v[0]; S[r][cb + 1] = v[1]; S[r][cb + 2] = v[2]; S[r][cb + 3] = v[3];
    }
    __syncthreads();
    // phase 2: bias add. Thread owns (b = t>>4, o in [o0, o0+32)).
    {
        int bb = t >> 4;
        int o0 = (t & 15) * 32;
        float bias[32];
#pragma unroll
        for (int c = 0; c < 32; c++) bias[c] = 0.f;
        for (int n = 0; n < 64; n++) {
            float a = attL[bb][n];
            const f4* rp = (const f4*)(relb + n * 512 + o0);
#pragma unroll
            for (int c = 0; c < 8; c++) {
                f4 rv = rp[c];
                bias[4 * c + 0] += a * rv[0]; bias[4 * c + 1] += a * rv[1];
                bias[4 * c + 2] += a * rv[2]; bias[4 * c + 3] += a * rv[3];
            }
        }
#pragma unroll
        for (int c = 0; c < 32; c++) S[o0 + c][bb] += bias[c];
    }
    __syncthreads();
    // phase 3: LN
    int b = t >> 4, j = t & 15;
    float s1 = 0.f, s2 = 0.f;
#pragma unroll
    for (int k = 0; k < 32; k++) {
        float v = S[j + 16 * k][b];
        s1 += v; s2 += v * v;
    }
#pragma unroll
    for (int off = 8; off; off >>= 1) {
        s1 += __shfl_down(s1, off, 16);
        s2 += __shfl_down(s2, off, 16);
    }
    int src = (t & 63) & ~15;
    s1 = __shfl(s1, src, 64);
    s2 = __shfl(s2, src, 64);
    float mu = s1 * (1.f / 512.f);
    float var = s2 * (1.f / 512.f) - mu * mu;
    float rs = rsqrtf(var + 1e-5f);
#pragma unroll
    for (int k = 0; k < 32; k++) {
        int o = j + 16 * k;
        out[(size_t)(b0 + b) * 512 + o] = (S[o][b] - mu) * rs;
    }
}

extern "C" void kernel_launch(void* const* d_in, const int* in_sizes, int n_in,
                              void* d_out, int out_size, void* d_ws, size_t ws_size,
                              hipStream_t stream) {
    (void)in_sizes; (void)n_in; (void)out_size; (void)ws_size;
    const float* emb      = (const float*)d_in[0];
    const int*   proj_ids = (const int*)d_in[1];
    const float* rel_att  = (const float*)d_in[2];
    const float* rel_base = (const float*)d_in[3];
    const float* rel_bias = (const float*)d_in[4];
    float* out = (float*)d_out;

    char* w = (char*)d_ws;
    unsigned short* embB  = (unsigned short*)(w + (1u << 20));
    unsigned short* rbT   = (unsigned short*)(w + 5u * (1u << 20));
    float*          gemmT = (float*)(w + 37u * (1u << 20));   // 2 slices of 8 MiB
    float*          g1    = gemmT + (size_t)512 * 4096;

    cvt_emb<<<dim3(2048), dim3(256), 0, stream>>>(emb, embB);
    transpose_rb<<<dim3(16, 16, 64), dim3(32, 8, 1), 0, stream>>>(rel_base, rbT);
    gemm_fold<<<dim3(1024), dim3(256), 0, stream>>>(embB, rbT, proj_ids, rel_att, gemmT);
    ln_kernel<<<dim3(256), dim3(256), 0, stream>>>(gemmT, g1, proj_ids, rel_att, rel_bias, out);
}

// Round 4
// 333.880 us; speedup vs baseline: 1.3201x; 1.3201x over previous
//
#include <hip/hip_runtime.h>

typedef float f4 __attribute__((ext_vector_type(4)));
typedef short s8 __attribute__((ext_vector_type(8)));
typedef unsigned short u16x4 __attribute__((ext_vector_type(4)));

// ---- ws layout (bytes) ----
// embB   : 1 MiB    .. 5 MiB   (4096*512 bf16)
// rbT    : 5 MiB    .. 37 MiB  (64*512*512 bf16, [n][o][i])
// gemmT  : 37 MiB   .. 53 MiB  (2 slices of 512*4096 f32, [o][b])

__device__ __forceinline__ unsigned short f2bf(float f) {
    unsigned int u = __float_as_uint(f);
    unsigned int r = (u + 0x7fffu + ((u >> 16) & 1u)) >> 16;
    return (unsigned short)r;
}

__global__ void cvt_emb(const float* __restrict__ e, unsigned short* __restrict__ eb) {
    int g = (blockIdx.x * 256 + threadIdx.x) * 4;
    f4 v = *(const f4*)(e + g);
    u16x4 o;
    o[0] = f2bf(v[0]); o[1] = f2bf(v[1]); o[2] = f2bf(v[2]); o[3] = f2bf(v[3]);
    *(u16x4*)(eb + g) = o;
}

// rbT[n][o][i] = bf16(rel_base[n][i][o])
__global__ void transpose_rb(const float* __restrict__ rb, unsigned short* __restrict__ rbT) {
    __shared__ float tl[32][33];
    int n = blockIdx.z, i0 = blockIdx.x * 32, o0 = blockIdx.y * 32;
    int tx = threadIdx.x, ty = threadIdx.y;      // 32 x 8
#pragma unroll
    for (int k = 0; k < 4; k++) {
        int i = ty + k * 8;
        tl[i][tx] = rb[((size_t)(n * 512 + i0 + i)) * 512 + o0 + tx];
    }
    __syncthreads();
#pragma unroll
    for (int k = 0; k < 4; k++) {
        int o = ty + k * 8;
        rbT[((size_t)(n * 512 + o0 + o)) * 512 + i0 + tx] = f2bf(tl[tx][o]);
    }
}

// Main fused GEMM, n-split x2, LDS-staged but BARRIER-FREE K-loop:
// each wave stages (global_load_lds) exactly the 16 o-rows it alone consumes,
// so buffer reuse needs only a per-wave s_waitcnt vmcnt(4) — no __syncthreads.
// gemmT[z][o][b] = sum_{n in half z} att[b,n] * sum_i emb[b,i]*rbT[n][o][i]
// block: 64 b (m) x 64 o; 4 waves, wave tile = 16 o x 64 m; K-chunks of 128 i.
// LDS = 32 KiB dbuf + 8 KiB attS = 40960 B -> 4 blocks/CU.
__global__ __launch_bounds__(256, 4) void gemm_fold(const unsigned short* __restrict__ embB,
                                                    const unsigned short* __restrict__ rbT,
                                                    const int* __restrict__ ids,
                                                    const float* __restrict__ rel_att,
                                                    float* __restrict__ gemmT) {
    __shared__ unsigned short bS[2][64 * 128];    // [buf][o_local*128 + i_local] (xor-swizzled)
    __shared__ float attS[64][32];                // [m][n ^ (m&31)] swizzle, no pad

    const int t = threadIdx.x;
    const int wv = t >> 6;
    const int ln = t & 63;
    const int q  = ln >> 4;     // quad 0..3
    const int lm = ln & 15;
    const int g  = blockIdx.x;
    const int o0 = (g & 7) * 64;                  // fastest -> XCD-aligned o slice
    const int m0 = ((g >> 3) & 63) * 64;
    const int nz = g >> 9;                        // n-half 0/1
    const int nbase = nz * 32;

    // stage att tile [64 m][32 n] (swizzled), gathered via ids: 8 per thread
#pragma unroll
    for (int k = 0; k < 8; k++) {
        int idx = t + 256 * k;
        int m = idx >> 5, n = idx & 31;
        attS[m][n ^ (m & 31)] = rel_att[(size_t)ids[m0 + m] * 64 + nbase + n];
    }
    __syncthreads();                              // the ONLY block barrier

    // async stage of one 64o x 128i bf16 tile; this wave's 4 chunks cover
    // rows [wv*16, wv*16+16) — wave-private producer/consumer.
    auto stage = [&](int s, int buf) {
        int ic = s >> 5, n = nbase + (s & 31);
#pragma unroll
        for (int j = 0; j < 4; j++) {
            int c   = wv * 4 + j;                 // chunk 0..15
            int r   = c * 4 + q;                  // o_local
            int c16 = (ln & 15) ^ (r & 15);       // logical i-chunk for this lane's slot
            const unsigned short* gp = rbT + (size_t)(n * 512 + o0 + r) * 512 + ic * 128 + c16 * 8;
            void* l = (char*)(&bS[buf][0]) + c * 1024;
            __builtin_amdgcn_global_load_lds((const __attribute__((address_space(1))) void*)gp,
                                             (__attribute__((address_space(3))) void*)l,
                                             16, 0, 0);
        }
    };

    f4 acc[4] = {f4{0,0,0,0}, f4{0,0,0,0}, f4{0,0,0,0}, f4{0,0,0,0}};
    s8 embF[4][4];

    stage(0, 0);

    for (int s = 0; s < 128; s++) {
        int ic = s >> 5, nl = s & 31;
        if (nl == 0) {
            // emb fragments for this i-chunk: register-resident across the n loop
#pragma unroll
            for (int ks = 0; ks < 4; ks++)
#pragma unroll
                for (int ms = 0; ms < 4; ms++)
                    embF[ks][ms] = *(const s8*)(embB + (size_t)(m0 + ms * 16 + lm) * 512
                                                + ic * 128 + ks * 32 + q * 8);
        }
        if (s + 1 < 128) {
            stage(s + 1, (s + 1) & 1);
            // wait until only the 4 just-issued loads remain -> tile s landed.
            // (embF global loads occasionally in queue make this conservative, not wrong.)
            asm volatile("s_waitcnt vmcnt(4)" ::: "memory");
        } else {
            asm volatile("s_waitcnt vmcnt(0)" ::: "memory");
        }

        const unsigned short* bp = &bS[s & 1][0];
        f4 an[4] = {f4{0,0,0,0}, f4{0,0,0,0}, f4{0,0,0,0}, f4{0,0,0,0}};
#pragma unroll
        for (int ks = 0; ks < 4; ks++) {
            int c16 = (ks * 4 + q) ^ lm;          // un-swizzle
            s8 aF = *(const s8*)(bp + (wv * 16 + lm) * 128 + c16 * 8);
#pragma unroll
            for (int ms = 0; ms < 4; ms++)
                an[ms] = __builtin_amdgcn_mfma_f32_16x16x32_bf16(aF, embF[ks][ms], an[ms], 0, 0, 0);
        }
#pragma unroll
        for (int ms = 0; ms < 4; ms++) {
            int row = ms * 16 + lm;
            float av = attS[row][nl ^ (row & 31)];   // broadcast within quad
            acc[ms] += av * an[ms];
        }
    }

    // epilogue: D[row=o][col=m] into this half's slice
    float* gT = gemmT + (size_t)nz * 512 * 4096;
#pragma unroll
    for (int ms = 0; ms < 4; ms++)
#pragma unroll
        for (int r = 0; r < 4; r++) {
            int o = o0 + wv * 16 + q * 4 + r;
            int m = m0 + ms * 16 + lm;
            gT[(size_t)o * 4096 + m] = acc[ms][r];
        }
}

// LayerNorm over o (512) per b: v = g0+g1+bias, bias computed in-kernel from
// att (gathered via ids) x rel_bias (L2-resident, 128 KB). Writes out[b][o].
__global__ __launch_bounds__(256) void ln_kernel(const float* __restrict__ g0,
                                                 const float* __restrict__ g1,
                                                 const int* __restrict__ ids,
                                                 const float* __restrict__ rel_att,
                                                 const float* __restrict__ relb,
                                                 float* __restrict__ out) {
    __shared__ float S[512][17];
    __shared__ float attL[16][65];
    int t = threadIdx.x;
    int b0 = blockIdx.x * 16;

    {   // load att tile [16 b][64 n]: 4 per thread, gathered
        int idx = t * 4;
        int b = idx >> 6, n = idx & 63;
        f4 v = *(const f4*)(rel_att + (size_t)ids[b0 + b] * 64 + n);
        attL[b][n] = v[0]; attL[b][n + 1] = v[1]; attL[b][n + 2] = v[2]; attL[b][n + 3] = v[3];
    }
    // phase 1: S[o][b] = g0 + g1
#pragma unroll
    for (int p = 0; p < 8; p++) {
        int r = p * 64 + (t >> 2);
        int cb = (t & 3) * 4;
        f4 a = *(const f4*)(g0 + (size_t)r * 4096 + b0 + cb);
        f4 b = *(const f4*)(g1 + (size_t)r * 4096 + b0 + cb);
        f4 v = a + b;
        S[r][cb + 0] = v[0]; S[r][cb + 1] = v[1]; S[r][cb + 2] = v[2]; S[r][cb + 3] = v[3];
    }
    __syncthreads();
    // phase 2: bias add. Thread owns (b = t>>4, o in [o0, o0+32)).
    {
        int bb = t >> 4;
        int o0 = (t & 15) * 32;
        float bias[32];
#pragma unroll
        for (int c = 0; c < 32; c++) bias[c] = 0.f;
        for (int n = 0; n < 64; n++) {
            float a = attL[bb][n];
            const f4* rp = (const f4*)(relb + n * 512 + o0);
#pragma unroll
            for (int c = 0; c < 8; c++) {
                f4 rv = rp[c];
                bias[4 * c + 0] += a * rv[0]; bias[4 * c + 1] += a * rv[1];
                bias[4 * c + 2] += a * rv[2]; bias[4 * c + 3] += a * rv[3];
            }
        }
#pragma unroll
        for (int c = 0; c < 32; c++) S[o0 + c][bb] += bias[c];
    }
    __syncthreads();
    // phase 3: LN
    int b = t >> 4, j = t & 15;
    float s1 = 0.f, s2 = 0.f;
#pragma unroll
    for (int k = 0; k < 32; k++) {
        float v = S[j + 16 * k][b];
        s1 += v; s2 += v * v;
    }
#pragma unroll
    for (int off = 8; off; off >>= 1) {
        s1 += __shfl_down(s1, off, 16);
        s2 += __shfl_down(s2, off, 16);
    }
    int src = (t & 63) & ~15;
    s1 = __shfl(s1, src, 64);
    s2 = __shfl(s2, src, 64);
    float mu = s1 * (1.f / 512.f);
    float var = s2 * (1.f / 512.f) - mu * mu;
    float rs = rsqrtf(var + 1e-5f);
#pragma unroll
    for (int k = 0; k < 32; k++) {
        int o = j + 16 * k;
        out[(size_t)(b0 + b) * 512 + o] = (S[o][b] - mu) * rs;
    }
}

extern "C" void kernel_launch(void* const* d_in, const int* in_sizes, int n_in,
                              void* d_out, int out_size, void* d_ws, size_t ws_size,
                              hipStream_t stream) {
    (void)in_sizes; (void)n_in; (void)out_size; (void)ws_size;
    const float* emb      = (const float*)d_in[0];
    const int*   proj_ids = (const int*)d_in[1];
    const float* rel_att  = (const float*)d_in[2];
    const float* rel_base = (const float*)d_in[3];
    const float* rel_bias = (const float*)d_in[4];
    float* out = (float*)d_out;

    char* w = (char*)d_ws;
    unsigned short* embB  = (unsigned short*)(w + (1u << 20));
    unsigned short* rbT   = (unsigned short*)(w + 5u * (1u << 20));
    float*          gemmT = (float*)(w + 37u * (1u << 20));   // 2 slices of 8 MiB
    float*          g1    = gemmT + (size_t)512 * 4096;

    cvt_emb<<<dim3(2048), dim3(256), 0, stream>>>(emb, embB);
    transpose_rb<<<dim3(16, 16, 64), dim3(32, 8, 1), 0, stream>>>(rel_base, rbT);
    gemm_fold<<<dim3(1024), dim3(256), 0, stream>>>(embB, rbT, proj_ids, rel_att, gemmT);
    ln_kernel<<<dim3(256), dim3(256), 0, stream>>>(gemmT, g1, proj_ids, rel_att, rel_bias, out);
}

// Round 5
// 321.926 us; speedup vs baseline: 1.3691x; 1.0371x over previous
//
#include <hip/hip_runtime.h>

typedef float f4 __attribute__((ext_vector_type(4)));
typedef short s8 __attribute__((ext_vector_type(8)));
typedef unsigned short u16x4 __attribute__((ext_vector_type(4)));

// ---- ws layout (bytes) ----
// embB   : 1 MiB    .. 5 MiB   (4096*512 bf16)
// rbT    : 5 MiB    .. 37 MiB  (64*512*512 bf16, [n][o][i])
// gemmT  : 37 MiB   .. 53 MiB  (2 slices of 512*4096 f32, [o][b])

__device__ __forceinline__ unsigned short f2bf(float f) {
    unsigned int u = __float_as_uint(f);
    unsigned int r = (u + 0x7fffu + ((u >> 16) & 1u)) >> 16;
    return (unsigned short)r;
}

// merged prep: blocks [0,2048) convert emb f32->bf16; blocks [2048,...) transpose rel_base
__global__ __launch_bounds__(256) void prep_kernel(const float* __restrict__ emb,
                                                   unsigned short* __restrict__ embB,
                                                   const float* __restrict__ rb,
                                                   unsigned short* __restrict__ rbT) {
    int bid = blockIdx.x;
    int t = threadIdx.x;
    if (bid < 2048) {
        int g = (bid * 256 + t) * 4;
        f4 v = *(const f4*)(emb + g);
        u16x4 o;
        o[0] = f2bf(v[0]); o[1] = f2bf(v[1]); o[2] = f2bf(v[2]); o[3] = f2bf(v[3]);
        *(u16x4*)(embB + g) = o;
        return;
    }
    __shared__ float tl[32][33];
    int b2 = bid - 2048;
    int n = b2 >> 8;
    int rem = b2 & 255;
    int i0 = (rem & 15) * 32, o0 = (rem >> 4) * 32;
    int tx = t & 31, ty = t >> 5;                 // 32 x 8
#pragma unroll
    for (int k = 0; k < 4; k++) {
        int i = ty + k * 8;
        tl[i][tx] = rb[((size_t)(n * 512 + i0 + i)) * 512 + o0 + tx];
    }
    __syncthreads();
#pragma unroll
    for (int k = 0; k < 4; k++) {
        int o = ty + k * 8;
        rbT[((size_t)(n * 512 + o0 + o)) * 512 + i0 + tx] = f2bf(tl[tx][o]);
    }
}

// Main fused GEMM, n-split x2, barrier-free K-loop, quad-buffered (prefetch dist 2):
// gemmT[z][o][b] = sum_{n in half z} att[b,n] * sum_i emb[b,i]*rbT[n][o][i]
// block: 64 b (m) x 64 o; 4 waves, wave tile = 16 o x 64 m; 64-i tiles (8 KiB).
// Each wave stages exactly its own 16 o-rows -> per-wave s_waitcnt vmcnt, no __syncthreads.
// Register budget kept < 128 so acc/an stay in VGPRs (no accvgpr fold traffic).
// LDS = 4*8 KiB bufs + 8 KiB attS = 40960 B -> 4 blocks/CU.
__global__ __launch_bounds__(256, 4) void gemm_fold(const unsigned short* __restrict__ embB,
                                                    const unsigned short* __restrict__ rbT,
                                                    const int* __restrict__ ids,
                                                    const float* __restrict__ rel_att,
                                                    float* __restrict__ gemmT) {
    __shared__ unsigned short bS[4][64 * 64];     // 4 bufs, [o_local*64 + i] (xor-swizzled 16B chunks)
    __shared__ float attS[32][64];                // [n][m] broadcast layout

    const int t = threadIdx.x;
    const int wv = t >> 6;
    const int ln = t & 63;
    const int q  = ln >> 4;     // quad 0..3
    const int lm = ln & 15;
    const int g  = blockIdx.x;
    const int o0 = (g & 7) * 64;                  // fastest -> XCD-aligned o slice
    const int m0 = ((g >> 3) & 63) * 64;
    const int nz = g >> 9;                        // n-half 0/1
    const int nbase = nz * 32;

    // stage att tile [32 n][64 m], gathered via ids: 8 per thread
#pragma unroll
    for (int k = 0; k < 8; k++) {
        int idx = t + 256 * k;
        int n = idx >> 6, m = idx & 63;
        attS[n][m] = rel_att[(size_t)ids[m0 + m] * 64 + nbase + n];
    }
    __syncthreads();                              // the ONLY block barrier

    // stage one 64o x 64i tile; wave stages chunks c = wv*2+{0,1} -> rows [wv*16, wv*16+16).
    // lane ln -> LDS slot c*1024 + ln*16 = row (c*8 + (ln>>3)), phys 16B-chunk (ln&7);
    // phys chunk p at row r holds logical i-chunk p ^ (r&7).
    const int srow = (ln >> 3);                   // 0..7 within chunk
    const int si8  = (ln & 7) ^ srow;             // logical i-chunk to fetch
    auto stage = [&](int s, int buf) {
        int ic = s >> 5, n = nbase + (s & 31);
#pragma unroll
        for (int j = 0; j < 2; j++) {
            int c = wv * 2 + j;
            int r = c * 8 + srow;
            const unsigned short* gp = rbT + (size_t)(n * 512 + o0 + r) * 512 + ic * 64 + si8 * 8;
            void* l = (char*)(&bS[buf][0]) + c * 1024;
            __builtin_amdgcn_global_load_lds((const __attribute__((address_space(1))) void*)gp,
                                             (__attribute__((address_space(3))) void*)l,
                                             16, 0, 0);
        }
    };

    const f4 z = {0.f, 0.f, 0.f, 0.f};
    f4 acc[4] = {z, z, z, z};
    s8 embF[2][4];

    // A-frag read offsets (within tile): row R = wv*16+lm, logical chunk ks*4+q,
    // phys = (ks*4+q) ^ (lm&7); addr = R*128 + phys*16.
    const int aOff0 = (wv * 16 + lm) * 128 + ((q) ^ (lm & 7)) * 16;     // ks=0
    const int aOff1 = aOff0 ^ 64;                                       // ks=1 (chunk ^4 -> byte ^64)

    stage(0, 0);
    stage(1, 1);

    for (int s = 0; s < 256; s++) {
        int nl = s & 31;
        if (nl == 0) {
            int ic = s >> 5;
#pragma unroll
            for (int ks = 0; ks < 2; ks++)
#pragma unroll
                for (int ms = 0; ms < 4; ms++)
                    embF[ks][ms] = *(const s8*)(embB + (size_t)(m0 + ms * 16 + lm) * 512
                                                + ic * 64 + ks * 32 + q * 8);
        }
        if (s + 2 < 256) {
            stage(s + 2, (s + 2) & 3);
            asm volatile("s_waitcnt vmcnt(4)" ::: "memory");   // tiles s+1,s+2 in flight; s landed
        } else if (s + 1 < 256) {
            asm volatile("s_waitcnt vmcnt(2)" ::: "memory");
        } else {
            asm volatile("s_waitcnt vmcnt(0)" ::: "memory");
        }

        const char* bp = (const char*)&bS[s & 3][0];
        s8 aF0 = *(const s8*)(bp + aOff0);
        s8 aF1 = *(const s8*)(bp + aOff1);
        f4 an[4];
#pragma unroll
        for (int ms = 0; ms < 4; ms++)
            an[ms] = __builtin_amdgcn_mfma_f32_16x16x32_bf16(aF0, embF[0][ms], z, 0, 0, 0);
#pragma unroll
        for (int ms = 0; ms < 4; ms++)
            an[ms] = __builtin_amdgcn_mfma_f32_16x16x32_bf16(aF1, embF[1][ms], an[ms], 0, 0, 0);
#pragma unroll
        for (int ms = 0; ms < 4; ms++) {
            float av = attS[nl][ms * 16 + lm];    // 4-way broadcast, immediate offsets
            acc[ms] += av * an[ms];
        }
    }

    // epilogue: D[row=o][col=m] into this half's slice
    float* gT = gemmT + (size_t)nz * 512 * 4096;
#pragma unroll
    for (int ms = 0; ms < 4; ms++)
#pragma unroll
        for (int r = 0; r < 4; r++) {
            int o = o0 + wv * 16 + q * 4 + r;
            int m = m0 + ms * 16 + lm;
            gT[(size_t)o * 4096 + m] = acc[ms][r];
        }
}

// LayerNorm over o (512) per b: v = g0+g1+bias, bias computed in-kernel from
// att (gathered) x rel_bias (L2-resident). 8 b per block, grid 512.
__global__ __launch_bounds__(256) void ln_kernel(const float* __restrict__ g0,
                                                 const float* __restrict__ g1,
                                                 const int* __restrict__ ids,
                                                 const float* __restrict__ rel_att,
                                                 const float* __restrict__ relb,
                                                 float* __restrict__ out) {
    __shared__ float S[512][9];
    __shared__ float attL[8][72];
    int t = threadIdx.x;
    int b0 = blockIdx.x * 8;

    {   // load att tile [8 b][64 n]: 2 per thread, gathered
        int idx = t * 2;
        int b = idx >> 6, n = idx & 63;
        const float* ap = rel_att + (size_t)ids[b0 + b] * 64 + n;
        attL[b][n] = ap[0];
        attL[b][n + 1] = ap[1];
    }
    // phase 1: S[o][b] = g0 + g1   (rows r = p*128 + t>>1, col-half ch = t&1)
#pragma unroll
    for (int p = 0; p < 4; p++) {
        int r = p * 128 + (t >> 1);
        int cb = (t & 1) * 4;
        f4 a = *(const f4*)(g0 + (size_t)r * 4096 + b0 + cb);
        f4 b = *(const f4*)(g1 + (size_t)r * 4096 + b0 + cb);
        f4 v = a + b;
        S[r][cb + 0] = v[0]; S[r][cb + 1] = v[1]; S[r][cb + 2] = v[2]; S[r][cb + 3] = v[3];
    }
    __syncthreads();
    // phase 2: bias add. Thread owns (b = t>>5, o in [oc, oc+16)).
    {
        int bb = t >> 5;
        int oc = (t & 31) * 16;
        f4 bias[4] = {f4{0,0,0,0}, f4{0,0,0,0}, f4{0,0,0,0}, f4{0,0,0,0}};
        for (int n = 0; n < 64; n++) {
            float a = attL[bb][n];
            const f4* rp = (const f4*)(relb + n * 512 + oc);
#pragma unroll
            for (int c = 0; c < 4; c++) bias[c] += a * rp[c];
        }
#pragma unroll
        for (int c = 0; c < 4; c++)
#pragma unroll
            for (int i = 0; i < 4; i++) S[oc + c * 4 + i][bb] += bias[c][i];
    }
    __syncthreads();
    // phase 3: LN. b = t>>5, j = t&31; o = j + 32k.
    int b = t >> 5, j = t & 31;
    float s1 = 0.f, s2 = 0.f;
#pragma unroll
    for (int k = 0; k < 16; k++) {
        float v = S[j + 32 * k][b];
        s1 += v; s2 += v * v;
    }
#pragma unroll
    for (int off = 16; off; off >>= 1) {
        s1 += __shfl_down(s1, off, 32);
        s2 += __shfl_down(s2, off, 32);
    }
    s1 = __shfl(s1, (t & 63) & ~31, 64);
    s2 = __shfl(s2, (t & 63) & ~31, 64);
    float mu = s1 * (1.f / 512.f);
    float var = s2 * (1.f / 512.f) - mu * mu;
    float rs = rsqrtf(var + 1e-5f);
#pragma unroll
    for (int k = 0; k < 16; k++) {
        int o = j + 32 * k;
        out[(size_t)(b0 + b) * 512 + o] = (S[o][b] - mu) * rs;
    }
}

extern "C" void kernel_launch(void* const* d_in, const int* in_sizes, int n_in,
                              void* d_out, int out_size, void* d_ws, size_t ws_size,
                              hipStream_t stream) {
    (void)in_sizes; (void)n_in; (void)out_size; (void)ws_size;
    const float* emb      = (const float*)d_in[0];
    const int*   proj_ids = (const int*)d_in[1];
    const float* rel_att  = (const float*)d_in[2];
    const float* rel_base = (const float*)d_in[3];
    const float* rel_bias = (const float*)d_in[4];
    float* out = (float*)d_out;

    char* w = (char*)d_ws;
    unsigned short* embB  = (unsigned short*)(w + (1u << 20));
    unsigned short* rbT   = (unsigned short*)(w + 5u * (1u << 20));
    float*          gemmT = (float*)(w + 37u * (1u << 20));   // 2 slices of 8 MiB
    float*          g1    = gemmT + (size_t)512 * 4096;

    prep_kernel<<<dim3(2048 + 16384), dim3(256), 0, stream>>>(emb, embB, rel_base, rbT);
    gemm_fold<<<dim3(1024), dim3(256), 0, stream>>>(embB, rbT, proj_ids, rel_att, gemmT);
    ln_kernel<<<dim3(512), dim3(256), 0, stream>>>(gemmT, g1, proj_ids, rel_att, rel_bias, out);
}